// Round 4
// baseline (1634.649 us; speedup 1.0000x reference)
//
#include <hip/hip_runtime.h>
#include <hip/hip_bf16.h>
#include <math.h>

#define B_TOTAL 65536
#define D 512
#define H 8
#define K 128
#define M 64
#define D2 1024

typedef __attribute__((ext_vector_type(8))) short short8v;   // 8 bf16 (4 VGPRs)
typedef __attribute__((ext_vector_type(4))) float f32x4;

__device__ __forceinline__ unsigned short f2bf(float f) {
    union { float f; unsigned u; } v; v.f = f;
    unsigned r = v.u + 0x7FFF + ((v.u >> 16) & 1);   // RNE
    return (unsigned short)(r >> 16);
}

__device__ __forceinline__ unsigned pk2(float a, float b) {
    float2 t; t.x = a; t.y = b;
    __hip_bfloat162 h = __float22bfloat162_rn(t);    // v_cvt_pk_bf16_f32
    union { __hip_bfloat162 h; unsigned u; } c; c.h = h;
    return c.u;
}

__device__ __forceinline__ short8v pack8(float4 a, float4 b) {
    union { unsigned u[4]; short8v v; } r;
    r.u[0] = pk2(a.x, a.y); r.u[1] = pk2(a.z, a.w);
    r.u[2] = pk2(b.x, b.y); r.u[3] = pk2(b.z, b.w);
    return r.v;
}

__device__ __forceinline__ float gelu_exact(float x) {
    return 0.5f * x * (1.0f + erff(x * 0.70710678118654752440f));
}

// ============== converter: weights -> fragment-linear bf16 in ws ==============
// W1T: [hd(8)][kblk(16)][nt(8)][lane(64)][j(8)]  elem j = W1[hd][32kb+8(l>>4)+j][16nt+(l&15)]
// W2T: [hd(8)][kblk(4)][nt(4)][lane][j]          elem j = W2[hd][32kb+8(l>>4)+j][16nt+(l&15)]
// gW1T:[kblk(32)][nt(32)][lane][j]               elem j = gW1[32kb+8(l>>4)+j][16nt+(l&15)]
__global__ void convert_weights(const float* __restrict__ W1, const float* __restrict__ W2,
                                const float* __restrict__ gW1,
                                unsigned short* __restrict__ W1T, unsigned short* __restrict__ W2T,
                                unsigned short* __restrict__ gW1T)
{
    int t = blockIdx.x * 256 + threadIdx.x;
    if (t < 65536) {
        int l = t & 63, nt = (t >> 6) & 7, kb = (t >> 9) & 15, hd = t >> 13;
        int n = 16 * nt + (l & 15);
        int k = 32 * kb + 8 * (l >> 4);
        const float* s = W1 + (size_t)hd * 65536 + (size_t)k * 128 + n;
        short8v o;
        #pragma unroll
        for (int j = 0; j < 8; ++j) o[j] = (short)f2bf(s[(size_t)j * 128]);
        *(short8v*)(W1T + (size_t)t * 8) = o;
    } else if (t < 65536 + 8192) {
        int u = t - 65536;
        int l = u & 63, nt = (u >> 6) & 3, kb = (u >> 8) & 3, hd = u >> 10;
        int m = 16 * nt + (l & 15);
        int k = 32 * kb + 8 * (l >> 4);
        const float* s = W2 + (size_t)hd * 8192 + (size_t)k * 64 + m;
        short8v o;
        #pragma unroll
        for (int j = 0; j < 8; ++j) o[j] = (short)f2bf(s[(size_t)j * 64]);
        *(short8v*)(W2T + (size_t)u * 8) = o;
    } else if (t < 65536 + 8192 + 65536) {
        int u = t - 73728;
        int l = u & 63, nt = (u >> 6) & 31, kb = u >> 11;
        int n = 16 * nt + (l & 15);
        int k = 32 * kb + 8 * (l >> 4);
        const float* s = gW1 + (size_t)k * 512 + n;
        short8v o;
        #pragma unroll
        for (int j = 0; j < 8; ++j) o[j] = (short)f2bf(s[(size_t)j * 512]);
        *(short8v*)(gW1T + (size_t)u * 8) = o;
    }
}

// ============== kernel H: per-head path, W1 LDS-resident ==============
// grid 4096: head=(bid>>3)&7, rb=((bid>>6)<<3)|(bid&7)  -> 8 head-blocks of one
// rowblock land consecutively on one XCD (input L2 reuse). Block = 128 batch rows,
// 4 waves; wave w owns rows [row0+32w, +32), rt0/1=text, rt2/3=image (in-lane cosine).
__global__ __launch_bounds__(256, 2) void head_kernel(
    const float* __restrict__ text, const float* __restrict__ image,
    const unsigned short* __restrict__ W1T, const float* __restrict__ b1,
    const float* __restrict__ ln1g, const float* __restrict__ ln1b,
    const unsigned short* __restrict__ W2T, const float* __restrict__ b2,
    float* __restrict__ out_pa)
{
    __shared__ __align__(16) unsigned short sW[32768];   // 64KB: half of W1[hd], frag-linear
    __shared__ __align__(16) unsigned short hB[4][640];  // per-wave transpose chunk

    const int tid = threadIdx.x;
    const int w = tid >> 6, lane = tid & 63, lg = lane >> 4, lc = lane & 15;
    const int bid = blockIdx.x;
    const int hd = (bid >> 3) & 7;
    const int rb = ((bid >> 6) << 3) | (bid & 7);
    const size_t row0 = (size_t)rb * 128 + 32 * w;       // this wave's batch base

    const char* W1b = (const char*)W1T + (size_t)hd * 131072;
    char* sWb = (char*)sW;

    // A row pointers (rt 0/1 text rows, rt 2/3 image rows; A-row = 16(rt&1)+lc)
    const float* arow[4];
    #pragma unroll
    for (int rt = 0; rt < 4; ++rt) {
        size_t br = row0 + 16 * (rt & 1) + lc;
        arow[rt] = ((rt >> 1) ? image : text) + br * 512;
    }

#define LOAD_A(dst, k0_) do { \
    _Pragma("unroll") \
    for (int rt_ = 0; rt_ < 4; ++rt_) { \
        const float* p_ = arow[rt_] + 32 * (k0_) + 8 * lg; \
        float4 u_ = *(const float4*)p_; \
        float4 v_ = *(const float4*)(p_ + 4); \
        dst[rt_] = pack8(u_, v_); \
    } } while (0)

    // ---- stage W1 phase 0 (kblk 0-7) ----
    #pragma unroll
    for (int i = 0; i < 16; ++i) {
        int off = (tid + 256 * i) * 16;
        *(float4*)(sWb + off) = *(const float4*)(W1b + off);
    }
    __syncthreads();

    f32x4 acc[4][8];
    #pragma unroll
    for (int rt = 0; rt < 4; ++rt)
        #pragma unroll
        for (int nt = 0; nt < 8; ++nt) acc[rt][nt] = (f32x4){0.f, 0.f, 0.f, 0.f};

    short8v aA[4], aB[4];
    LOAD_A(aA, 0);

    #pragma unroll
    for (int k0 = 0; k0 < 8; ++k0) {
        short8v* cur = (k0 & 1) ? aB : aA;
        short8v* nxt = (k0 & 1) ? aA : aB;
        LOAD_A(nxt, k0 + 1);
        const char* bb = sWb + k0 * 8192 + lane * 16;
        #pragma unroll
        for (int nt = 0; nt < 8; ++nt) {
            short8v bf_ = *(const short8v*)(bb + nt * 1024);
            #pragma unroll
            for (int rt = 0; rt < 4; ++rt)
                acc[rt][nt] = __builtin_amdgcn_mfma_f32_16x16x32_bf16(cur[rt], bf_, acc[rt][nt], 0, 0, 0);
        }
    }
    __syncthreads();
    // ---- stage W1 phase 1 (kblk 8-15) ----
    #pragma unroll
    for (int i = 0; i < 16; ++i) {
        int off = (tid + 256 * i) * 16;
        *(float4*)(sWb + off) = *(const float4*)(W1b + 65536 + off);
    }
    __syncthreads();
    #pragma unroll
    for (int k0 = 8; k0 < 16; ++k0) {
        short8v* cur = (k0 & 1) ? aB : aA;
        short8v* nxt = (k0 & 1) ? aA : aB;
        if (k0 < 15) LOAD_A(nxt, k0 + 1);
        const char* bb = sWb + (k0 - 8) * 8192 + lane * 16;
        #pragma unroll
        for (int nt = 0; nt < 8; ++nt) {
            short8v bf_ = *(const short8v*)(bb + nt * 1024);
            #pragma unroll
            for (int rt = 0; rt < 4; ++rt)
                acc[rt][nt] = __builtin_amdgcn_mfma_f32_16x16x32_bf16(cur[rt], bf_, acc[rt][nt], 0, 0, 0);
        }
    }
#undef LOAD_A

    // ---- + b1, LN stats ----
    #pragma unroll
    for (int nt = 0; nt < 8; ++nt) {
        float bv = b1[hd * 128 + 16 * nt + lc];
        #pragma unroll
        for (int rt = 0; rt < 4; ++rt)
            #pragma unroll
            for (int reg = 0; reg < 4; ++reg) acc[rt][nt][reg] += bv;
    }
    float mu[4][4], rsig[4][4];
    #pragma unroll
    for (int rt = 0; rt < 4; ++rt)
        #pragma unroll
        for (int reg = 0; reg < 4; ++reg) {
            float s = 0.f, s2 = 0.f;
            #pragma unroll
            for (int nt = 0; nt < 8; ++nt) { float v = acc[rt][nt][reg]; s += v; s2 += v * v; }
            #pragma unroll
            for (int off = 1; off < 16; off <<= 1) {
                s += __shfl_xor(s, off, 64);
                s2 += __shfl_xor(s2, off, 64);
            }
            float m = s * (1.0f / 128.0f);
            float var = s2 * (1.0f / 128.0f) - m * m;
            mu[rt][reg] = m;
            rsig[rt][reg] = rsqrtf(var + 1e-5f);
        }

    // ---- LN apply + GELU ----
    #pragma unroll
    for (int nt = 0; nt < 8; ++nt) {
        float gv = ln1g[hd * 128 + 16 * nt + lc];
        float bv = ln1b[hd * 128 + 16 * nt + lc];
        #pragma unroll
        for (int rt = 0; rt < 4; ++rt)
            #pragma unroll
            for (int reg = 0; reg < 4; ++reg) {
                float v = (acc[rt][nt][reg] - mu[rt][reg]) * rsig[rt][reg] * gv + bv;
                acc[rt][nt][reg] = gelu_exact(v);
            }
    }

    // ---- GEMM2 via wave-private LDS transpose chunks; W2 frags from L2 ----
    const char* W2b = (const char*)W2T;
    unsigned short* hb = &hB[w][0];
    f32x4 acc2[4][4];
    #pragma unroll
    for (int rt = 0; rt < 4; ++rt)
        #pragma unroll
        for (int nt2 = 0; nt2 < 4; ++nt2) acc2[rt][nt2] = (f32x4){0.f, 0.f, 0.f, 0.f};

    #pragma unroll
    for (int kb = 0; kb < 4; ++kb) {
        short8v bf2[4];
        #pragma unroll
        for (int nt2 = 0; nt2 < 4; ++nt2)
            bf2[nt2] = *(const short8v*)(W2b + hd * 16384 + kb * 4096 + nt2 * 1024 + lane * 16);
        #pragma unroll
        for (int rt = 0; rt < 4; ++rt) {
            #pragma unroll
            for (int ntl = 0; ntl < 2; ++ntl) {
                int nt = 2 * kb + ntl;
                int kk = 16 * ntl + lc;
                #pragma unroll
                for (int reg = 0; reg < 4; ++reg)
                    hb[(4 * lg + reg) * 40 + kk] = f2bf(acc[rt][nt][reg]);
            }
            short8v af2 = *(const short8v*)((const char*)hb + lc * 80 + 16 * lg);
            #pragma unroll
            for (int nt2 = 0; nt2 < 4; ++nt2)
                acc2[rt][nt2] = __builtin_amdgcn_mfma_f32_16x16x32_bf16(af2, bf2[nt2], acc2[rt][nt2], 0, 0, 0);
        }
    }

    // ---- + b2, norms + cosine (in-lane text rt <-> image rt+2) ----
    #pragma unroll
    for (int nt2 = 0; nt2 < 4; ++nt2) {
        float bv = b2[hd * 64 + 16 * nt2 + lc];
        #pragma unroll
        for (int rt = 0; rt < 4; ++rt)
            #pragma unroll
            for (int reg = 0; reg < 4; ++reg) acc2[rt][nt2][reg] += bv;
    }
    #pragma unroll
    for (int rt = 0; rt < 2; ++rt)
        #pragma unroll
        for (int reg = 0; reg < 4; ++reg) {
            float nt_ = 0.f, ni_ = 0.f, pr = 0.f;
            #pragma unroll
            for (int nt2 = 0; nt2 < 4; ++nt2) {
                float a = acc2[rt][nt2][reg];
                float b = acc2[rt + 2][nt2][reg];
                nt_ += a * a; ni_ += b * b; pr += a * b;
            }
            #pragma unroll
            for (int off = 1; off < 16; off <<= 1) {
                nt_ += __shfl_xor(nt_, off, 64);
                ni_ += __shfl_xor(ni_, off, 64);
                pr  += __shfl_xor(pr,  off, 64);
            }
            if (lc == 0) {
                int bl = 16 * rt + 4 * lg + reg;     // 0..31 within wave's rows
                float denom = fmaxf(sqrtf(nt_), 1e-12f) * fmaxf(sqrtf(ni_), 1e-12f);
                out_pa[(row0 + bl) * 8 + hd] = pr / denom;
            }
        }
}

// ============== kernel G: global path, gW1 k-chunked through dbuf LDS ==============
// 1024 blocks x 512 threads; block = 64 rows x 512 cols. Wave w: rg=w>>1 (16 rows),
// cg=w&1 (256 cols). 32 chunks of k=32; chunk c<16 text, else image.
__global__ __launch_bounds__(512, 2) void global_kernel(
    const float* __restrict__ text, const float* __restrict__ image,
    const unsigned short* __restrict__ gW1T, const float* __restrict__ gb1,
    const float* __restrict__ glng, const float* __restrict__ glnb,
    const float* __restrict__ gW2, const float* __restrict__ gb2,
    const float* __restrict__ aw, const float* __restrict__ pa,
    float* __restrict__ out_conflict)
{
    __shared__ __align__(16) unsigned short sW[2][16384];  // 2 x 32KB chunk dbuf
    __shared__ float sStat[2][64][2];
    __shared__ float sDot[2][64];

    const int tid = threadIdx.x;
    const int w = tid >> 6, lane = tid & 63, lg = lane >> 4, lc = lane & 15;
    const int rg = w >> 1, cg = w & 1;
    const size_t row0 = (size_t)blockIdx.x * 64;

    const char* gWb = (const char*)gW1T;
    const float* trow = text + (row0 + 16 * rg + lc) * 512;
    const float* irow = image + (row0 + 16 * rg + lc) * 512;

#define STAGE_G(c_, bi_) do { \
    const char* s_ = gWb + (size_t)(c_) * 32768 + tid * 64; \
    char* d_ = (char*)sW + (bi_) * 32768 + tid * 64; \
    _Pragma("unroll") \
    for (int q_ = 0; q_ < 4; ++q_) \
        *(float4*)(d_ + 16 * q_) = *(const float4*)(s_ + 16 * q_); \
} while (0)

#define LOAD_AG(dst, c_) do { \
    const float* p_ = ((c_) < 16 ? trow : irow) + 32 * ((c_) & 15) + 8 * lg; \
    float4 u_ = *(const float4*)p_; \
    float4 v_ = *(const float4*)(p_ + 4); \
    dst = pack8(u_, v_); \
} while (0)

    f32x4 acc[16];
    #pragma unroll
    for (int nt = 0; nt < 16; ++nt) acc[nt] = (f32x4){0.f, 0.f, 0.f, 0.f};

    short8v gA, gB;
    STAGE_G(0, 0);
    LOAD_AG(gA, 0);
    __syncthreads();

    #pragma unroll
    for (int c = 0; c < 32; ++c) {
        short8v curA = (c & 1) ? gB : gA;
        if (c < 31) {
            STAGE_G(c + 1, (c + 1) & 1);
            if (c & 1) { LOAD_AG(gA, c + 1); } else { LOAD_AG(gB, c + 1); }
        }
        const char* bb = (const char*)sW + (c & 1) * 32768 + (16 * cg) * 1024 + lane * 16;
        #pragma unroll
        for (int nt = 0; nt < 16; ++nt) {
            short8v bf_ = *(const short8v*)(bb + nt * 1024);
            acc[nt] = __builtin_amdgcn_mfma_f32_16x16x32_bf16(curA, bf_, acc[nt], 0, 0, 0);
        }
        __syncthreads();
    }
#undef STAGE_G
#undef LOAD_AG

    // ---- + gb1, LN stats partials (cols 256cg+16nt+lc) ----
    #pragma unroll
    for (int nt = 0; nt < 16; ++nt) {
        float bv = gb1[256 * cg + 16 * nt + lc];
        #pragma unroll
        for (int reg = 0; reg < 4; ++reg) acc[nt][reg] += bv;
    }
    #pragma unroll
    for (int reg = 0; reg < 4; ++reg) {
        float s = 0.f, s2 = 0.f;
        #pragma unroll
        for (int nt = 0; nt < 16; ++nt) { float v = acc[nt][reg]; s += v; s2 += v * v; }
        #pragma unroll
        for (int off = 1; off < 16; off <<= 1) {
            s += __shfl_xor(s, off, 64);
            s2 += __shfl_xor(s2, off, 64);
        }
        if (lc == 0) {
            int r = 16 * rg + 4 * lg + reg;
            sStat[cg][r][0] = s;
            sStat[cg][r][1] = s2;
        }
    }
    __syncthreads();

    float mug[4], rsg[4];
    #pragma unroll
    for (int reg = 0; reg < 4; ++reg) {
        int r = 16 * rg + 4 * lg + reg;
        float s = sStat[0][r][0] + sStat[1][r][0];
        float s2 = sStat[0][r][1] + sStat[1][r][1];
        float m = s * (1.0f / 512.0f);
        float var = s2 * (1.0f / 512.0f) - m * m;
        mug[reg] = m;
        rsg[reg] = rsqrtf(var + 1e-5f);
    }

    // ---- LN + GELU + dot(gW2) ----
    float dp[4] = {0.f, 0.f, 0.f, 0.f};
    #pragma unroll
    for (int nt = 0; nt < 16; ++nt) {
        int col = 256 * cg + 16 * nt + lc;
        float gv = glng[col], bv = glnb[col], wv = gW2[col];
        #pragma unroll
        for (int reg = 0; reg < 4; ++reg) {
            float v = (acc[nt][reg] - mug[reg]) * rsg[reg] * gv + bv;
            dp[reg] += gelu_exact(v) * wv;
        }
    }
    #pragma unroll
    for (int reg = 0; reg < 4; ++reg) {
        float d = dp[reg];
        #pragma unroll
        for (int off = 1; off < 16; off <<= 1) d += __shfl_xor(d, off, 64);
        if (lc == 0) sDot[cg][16 * rg + 4 * lg + reg] = d;
    }
    __syncthreads();

    // ---- conflict epilogue ----
    if (tid < 64) {
        int r = tid;
        float z = sDot[0][r] + sDot[1][r] + gb2[0];
        float gs = 1.0f / (1.0f + expf(-z));
        float wv[8], mx = -1e30f;
        #pragma unroll
        for (int i = 0; i < 8; ++i) { wv[i] = aw[i]; mx = fmaxf(mx, wv[i]); }
        float sum = 0.f;
        #pragma unroll
        for (int i = 0; i < 8; ++i) { wv[i] = expf(wv[i] - mx); sum += wv[i]; }
        float inv = 1.0f / sum;
        const float* par = pa + (row0 + r) * 8;
        float wsim = 0.f;
        #pragma unroll
        for (int i = 0; i < 8; ++i) wsim += par[i] * wv[i] * inv;
        float conf = 1.0f - (0.7f * wsim + 0.3f * gs);
        out_conflict[row0 + r] = fminf(fmaxf(conf, 0.0f), 1.0f);
    }
}

extern "C" void kernel_launch(void* const* d_in, const int* in_sizes, int n_in,
                              void* d_out, int out_size, void* d_ws, size_t ws_size,
                              hipStream_t stream) {
    const float* text  = (const float*)d_in[0];
    const float* image = (const float*)d_in[1];
    const float* W1    = (const float*)d_in[2];
    const float* b1    = (const float*)d_in[3];
    const float* ln1g  = (const float*)d_in[4];
    const float* ln1b  = (const float*)d_in[5];
    const float* W2    = (const float*)d_in[6];
    const float* b2    = (const float*)d_in[7];
    const float* aw    = (const float*)d_in[8];
    const float* gW1   = (const float*)d_in[9];
    const float* gb1   = (const float*)d_in[10];
    const float* glng  = (const float*)d_in[11];
    const float* glnb  = (const float*)d_in[12];
    const float* gW2   = (const float*)d_in[13];
    const float* gb2   = (const float*)d_in[14];

    unsigned short* W1T  = (unsigned short*)d_ws;                          // 1MB
    unsigned short* W2T  = (unsigned short*)((char*)d_ws + 1048576);       // 128KB
    unsigned short* gW1T = (unsigned short*)((char*)d_ws + 1179648);       // 1MB

    float* out = (float*)d_out;
    float* out_pa = out + B_TOTAL;

    convert_weights<<<544, 256, 0, stream>>>(W1, W2, gW1, W1T, W2T, gW1T);
    head_kernel<<<4096, 256, 0, stream>>>(text, image, W1T, b1, ln1g, ln1b, W2T, b2, out_pa);
    global_kernel<<<1024, 512, 0, stream>>>(text, image, gW1T, gb1, glng, glnb, gW2, gb2,
                                            aw, out_pa, out);
}

// Round 5
// 988.922 us; speedup vs baseline: 1.6530x; 1.6530x over previous
//
#include <hip/hip_runtime.h>
#include <hip/hip_bf16.h>
#include <math.h>

#define B_TOTAL 65536
#define D 512
#define H 8
#define K 128
#define M 64
#define D2 1024

typedef __attribute__((ext_vector_type(8))) short short8v;   // 8 bf16 (4 VGPRs)
typedef __attribute__((ext_vector_type(4))) float f32x4;

__device__ __forceinline__ unsigned short f2bf(float f) {
    union { float f; unsigned u; } v; v.f = f;
    unsigned r = v.u + 0x7FFF + ((v.u >> 16) & 1);   // RNE
    return (unsigned short)(r >> 16);
}

__device__ __forceinline__ unsigned pk2(float a, float b) {
    float2 t; t.x = a; t.y = b;
    __hip_bfloat162 h = __float22bfloat162_rn(t);    // v_cvt_pk_bf16_f32
    union { __hip_bfloat162 h; unsigned u; } c; c.h = h;
    return c.u;
}

__device__ __forceinline__ short8v pack8(float4 a, float4 b) {
    union { unsigned u[4]; short8v v; } r;
    r.u[0] = pk2(a.x, a.y); r.u[1] = pk2(a.z, a.w);
    r.u[2] = pk2(b.x, b.y); r.u[3] = pk2(b.z, b.w);
    return r.v;
}

__device__ __forceinline__ float gelu_exact(float x) {
    return 0.5f * x * (1.0f + erff(x * 0.70710678118654752440f));
}

__device__ __forceinline__ void glds16(const void* g, void* l) {
    __builtin_amdgcn_global_load_lds(
        (const __attribute__((address_space(1))) unsigned int*)g,
        (__attribute__((address_space(3))) unsigned int*)l, 16, 0, 0);
}

// ============== converter: weights -> fragment/chunk-linear bf16 in ws ==============
// W1c: chunk c=(hd>>2)*16+kb: [c(32)][h2=hd&3][nt(8)][lane(64)][j(8)]  (32KB chunks)
//      elem j = W1[hd][32kb+8(l>>4)+j][16nt+(l&15)]
// W2T: [hd(8)][kb(4)][nt2(4)][lane][j]   elem j = W2[hd][32kb+8(l>>4)+j][16nt2+(l&15)]
// gW1T:[kk(32)][nt(32)][lane][j]         elem j = gW1[32kk+8(l>>4)+j][16nt+(l&15)]
__global__ void convert_weights(const float* __restrict__ W1, const float* __restrict__ W2,
                                const float* __restrict__ gW1,
                                unsigned short* __restrict__ W1c, unsigned short* __restrict__ W2T,
                                unsigned short* __restrict__ gW1T)
{
    int t = blockIdx.x * 256 + threadIdx.x;
    if (t < 65536) {
        int l = t & 63, nt = (t >> 6) & 7, kb = (t >> 9) & 15, hd = t >> 13;
        int n = 16 * nt + (l & 15);
        int k = 32 * kb + 8 * (l >> 4);
        const float* s = W1 + (size_t)hd * 65536 + (size_t)k * 128 + n;
        short8v o;
        #pragma unroll
        for (int j = 0; j < 8; ++j) o[j] = (short)f2bf(s[(size_t)j * 128]);
        size_t u = ((((size_t)(hd >> 2) * 16 + kb) * 4 + (hd & 3)) * 8 + nt) * 64 + l;
        *(short8v*)(W1c + u * 8) = o;
    } else if (t < 65536 + 8192) {
        int u = t - 65536;
        int l = u & 63, nt = (u >> 6) & 3, kb = (u >> 8) & 3, hd = u >> 10;
        int m = 16 * nt + (l & 15);
        int k = 32 * kb + 8 * (l >> 4);
        const float* s = W2 + (size_t)hd * 8192 + (size_t)k * 64 + m;
        short8v o;
        #pragma unroll
        for (int j = 0; j < 8; ++j) o[j] = (short)f2bf(s[(size_t)j * 64]);
        *(short8v*)(W2T + (size_t)u * 8) = o;
    } else if (t < 65536 + 8192 + 65536) {
        int u = t - 73728;
        int l = u & 63, nt = (u >> 6) & 31, kb = u >> 11;
        int n = 16 * nt + (l & 15);
        int k = 32 * kb + 8 * (l >> 4);
        const float* s = gW1 + (size_t)k * 512 + n;
        short8v o;
        #pragma unroll
        for (int j = 0; j < 8; ++j) o[j] = (short)f2bf(s[(size_t)j * 512]);
        *(short8v*)(gW1T + (size_t)u * 8) = o;
    }
}

// ============== fused kernel ==============
// 2048 blocks x 512 threads (8 waves). 32 batch rows/block.
// sX: 64 A-rows (0-31 text, 32-63 image) x 512, bf16 swizzled, resident.
// Weights stream through sW (2 x 32KB dbuf) via global_load_lds.
// GEMM1 half p: heads 4p..4p+3; wave w -> head 4p+(w&3), rows (w>>2)*16..+16.
// gW1 phase: 32 chunks; wave w -> cols 64w..64w+63, all 32 rows.
__global__ __launch_bounds__(512, 2) void fused_all(
    const float* __restrict__ text, const float* __restrict__ image,
    const unsigned short* __restrict__ W1c, const float* __restrict__ b1,
    const float* __restrict__ ln1g, const float* __restrict__ ln1b,
    const unsigned short* __restrict__ W2T, const float* __restrict__ b2,
    const unsigned short* __restrict__ gW1T, const float* __restrict__ gb1,
    const float* __restrict__ glng, const float* __restrict__ glnb,
    const float* __restrict__ gW2, const float* __restrict__ gb2,
    const float* __restrict__ aw,
    float* __restrict__ out_conflict, float* __restrict__ out_pa)
{
    __shared__ __align__(16) unsigned short sX[64 * 512];   // 64KB A-tile
    __shared__ __align__(16) unsigned short sW[2][16384];   // 2x32KB weight chunks
    __shared__ __align__(16) unsigned short hB[8][640];     // per-wave transpose scratch
    __shared__ float sStat[8][32][2];
    __shared__ float sDot[8][32];
    __shared__ float sPa[32][8];

    const int tid = threadIdx.x;
    const int w = tid >> 6, lane = tid & 63, lg = lane >> 4, lc = lane & 15;
    const int h2 = w & 3, s = w >> 2;
    const size_t row0 = (size_t)blockIdx.x * 32;

    const char* sXb = (const char*)sX;
    char* sWb = (char*)sW;
    const char* W1b = (const char*)W1c;
    const char* gWb = (const char*)gW1T;
    const char* W2b = (const char*)W2T;

#define STAGE(bi_, base_, cid_) do { \
    const char* s_ = (base_) + (size_t)(cid_) * 32768 + w * 4096 + lane * 16; \
    char* d_ = sWb + (bi_) * 32768 + w * 4096; \
    _Pragma("unroll") \
    for (int i_ = 0; i_ < 4; ++i_) \
        glds16(s_ + i_ * 1024, d_ + i_ * 1024); \
} while (0)

    // ---- stage A-tile (rows 0-31 text, 32-63 image), swizzled bf16 ----
    #pragma unroll
    for (int i = 0; i < 16; ++i) {
        int idx = tid + 512 * i;                // 0..8191 float4 units
        int r = idx >> 7;
        int c4 = idx & 127;
        const float* src = (r < 32) ? (text + (row0 + r) * 512 + 4 * c4)
                                    : (image + (row0 + (r - 32)) * 512 + 4 * c4);
        float4 v = *(const float4*)src;
        uint2 pk;
        pk.x = pk2(v.x, v.y);
        pk.y = pk2(v.z, v.w);
        int byteoff = r * 1024 + ((8 * c4) ^ ((r & 7) << 4));
        *(uint2*)((char*)sX + byteoff) = pk;
    }
    STAGE(0, W1b, 0);                           // GEMM1 chunk (p=0,k0=0)
    __syncthreads();

    // ================= head path: two N-halves =================
    for (int p = 0; p < 2; ++p) {
        const int hd = 4 * p + h2;

        // prefetch W2 frags for GEMM2 (used ~15kcy later)
        short8v w2f[4][4];
        #pragma unroll
        for (int kb = 0; kb < 4; ++kb)
            #pragma unroll
            for (int nt2 = 0; nt2 < 4; ++nt2)
                w2f[kb][nt2] = *(const short8v*)(W2b + hd * 16384 + kb * 4096 + nt2 * 1024 + lane * 16);

        f32x4 acc[2][8];
        #pragma unroll
        for (int rt = 0; rt < 2; ++rt)
            #pragma unroll
            for (int nt = 0; nt < 8; ++nt) acc[rt][nt] = (f32x4){0.f, 0.f, 0.f, 0.f};

        #pragma unroll
        for (int k0 = 0; k0 < 16; ++k0) {
            // prefetch next chunk (or next phase's first chunk)
            if (k0 < 15)      STAGE((k0 + 1) & 1, W1b, p * 16 + k0 + 1);
            else if (p == 0)  STAGE(0, W1b, 16);
            else              STAGE(0, gWb, 0);

            // compute on current chunk
            short8v af[2];
            #pragma unroll
            for (int rt = 0; rt < 2; ++rt) {
                int a = rt * 32 + s * 16 + lc;
                af[rt] = *(const short8v*)(sXb + a * 1024 + ((64 * k0 + 16 * lg) ^ ((a & 7) << 4)));
            }
            const char* bb = sWb + (k0 & 1) * 32768 + h2 * 8192 + lane * 16;
            #pragma unroll
            for (int nt = 0; nt < 8; ++nt) {
                short8v bf_ = *(const short8v*)(bb + nt * 1024);
                acc[0][nt] = __builtin_amdgcn_mfma_f32_16x16x32_bf16(af[0], bf_, acc[0][nt], 0, 0, 0);
                acc[1][nt] = __builtin_amdgcn_mfma_f32_16x16x32_bf16(af[1], bf_, acc[1][nt], 0, 0, 0);
            }
            __syncthreads();
        }

        // ---- + b1, LN stats ----
        #pragma unroll
        for (int nt = 0; nt < 8; ++nt) {
            float bv = b1[hd * 128 + 16 * nt + lc];
            #pragma unroll
            for (int rt = 0; rt < 2; ++rt)
                #pragma unroll
                for (int reg = 0; reg < 4; ++reg) acc[rt][nt][reg] += bv;
        }
        float mu[2][4], rsig[2][4];
        #pragma unroll
        for (int rt = 0; rt < 2; ++rt)
            #pragma unroll
            for (int reg = 0; reg < 4; ++reg) {
                float s1 = 0.f, s2 = 0.f;
                #pragma unroll
                for (int nt = 0; nt < 8; ++nt) { float v = acc[rt][nt][reg]; s1 += v; s2 += v * v; }
                #pragma unroll
                for (int off = 1; off < 16; off <<= 1) {
                    s1 += __shfl_xor(s1, off, 64);
                    s2 += __shfl_xor(s2, off, 64);
                }
                float m = s1 * (1.0f / 128.0f);
                float var = s2 * (1.0f / 128.0f) - m * m;
                mu[rt][reg] = m;
                rsig[rt][reg] = rsqrtf(var + 1e-5f);
            }

        // ---- LN apply + GELU ----
        #pragma unroll
        for (int nt = 0; nt < 8; ++nt) {
            float gv = ln1g[hd * 128 + 16 * nt + lc];
            float bv = ln1b[hd * 128 + 16 * nt + lc];
            #pragma unroll
            for (int rt = 0; rt < 2; ++rt)
                #pragma unroll
                for (int reg = 0; reg < 4; ++reg) {
                    float v = (acc[rt][nt][reg] - mu[rt][reg]) * rsig[rt][reg] * gv + bv;
                    acc[rt][nt][reg] = gelu_exact(v);
                }
        }

        // ---- GEMM2 via wave-private LDS transpose chunks ----
        unsigned short* hb = &hB[w][0];
        f32x4 acc2[2][4];
        #pragma unroll
        for (int rt = 0; rt < 2; ++rt)
            #pragma unroll
            for (int nt2 = 0; nt2 < 4; ++nt2) acc2[rt][nt2] = (f32x4){0.f, 0.f, 0.f, 0.f};

        #pragma unroll
        for (int kb = 0; kb < 4; ++kb) {
            #pragma unroll
            for (int rt = 0; rt < 2; ++rt) {
                #pragma unroll
                for (int ntl = 0; ntl < 2; ++ntl) {
                    int nt = 2 * kb + ntl;
                    int kk = 16 * ntl + lc;
                    #pragma unroll
                    for (int reg = 0; reg < 4; ++reg)
                        hb[(4 * lg + reg) * 40 + kk] = f2bf(acc[rt][nt][reg]);
                }
                short8v af2 = *(const short8v*)((const char*)hb + lc * 80 + 16 * lg);
                #pragma unroll
                for (int nt2 = 0; nt2 < 4; ++nt2)
                    acc2[rt][nt2] = __builtin_amdgcn_mfma_f32_16x16x32_bf16(af2, w2f[kb][nt2], acc2[rt][nt2], 0, 0, 0);
            }
        }

        // ---- + b2, norms + cosine (in-lane rt0=text <-> rt1=image) ----
        #pragma unroll
        for (int nt2 = 0; nt2 < 4; ++nt2) {
            float bv = b2[hd * 64 + 16 * nt2 + lc];
            #pragma unroll
            for (int rt = 0; rt < 2; ++rt)
                #pragma unroll
                for (int reg = 0; reg < 4; ++reg) acc2[rt][nt2][reg] += bv;
        }
        #pragma unroll
        for (int reg = 0; reg < 4; ++reg) {
            float nt_ = 0.f, ni_ = 0.f, pr = 0.f;
            #pragma unroll
            for (int nt2 = 0; nt2 < 4; ++nt2) {
                float a = acc2[0][nt2][reg];
                float b = acc2[1][nt2][reg];
                nt_ += a * a; ni_ += b * b; pr += a * b;
            }
            #pragma unroll
            for (int off = 1; off < 16; off <<= 1) {
                nt_ += __shfl_xor(nt_, off, 64);
                ni_ += __shfl_xor(ni_, off, 64);
                pr  += __shfl_xor(pr,  off, 64);
            }
            if (lc == 0) {
                int bl = s * 16 + 4 * lg + reg;      // 0..31
                float denom = fmaxf(sqrtf(nt_), 1e-12f) * fmaxf(sqrtf(ni_), 1e-12f);
                float cosv = pr / denom;
                out_pa[(row0 + bl) * 8 + hd] = cosv;
                sPa[bl][hd] = cosv;
            }
        }
        __syncthreads();   // hB/sPa settle; staged next-phase chunk already drained at loop-end barrier
    }

    // ================= global path: 32 chunks, wave w -> cols 64w..64w+63 =================
    {
        f32x4 accg[2][4];
        #pragma unroll
        for (int rt = 0; rt < 2; ++rt)
            #pragma unroll
            for (int nt = 0; nt < 4; ++nt) accg[rt][nt] = (f32x4){0.f, 0.f, 0.f, 0.f};

        #pragma unroll
        for (int kk = 0; kk < 32; ++kk) {
            if (kk < 31) STAGE((kk + 1) & 1, gWb, kk + 1);

            int rbase = (kk < 16) ? 0 : 32;
            int k0 = kk & 15;
            short8v af[2];
            #pragma unroll
            for (int rt = 0; rt < 2; ++rt) {
                int a = rbase + 16 * rt + lc;
                af[rt] = *(const short8v*)(sXb + a * 1024 + ((64 * k0 + 16 * lg) ^ ((a & 7) << 4)));
            }
            const char* bb = sWb + (kk & 1) * 32768 + (4 * w) * 1024 + lane * 16;
            #pragma unroll
            for (int nt = 0; nt < 4; ++nt) {
                short8v bf_ = *(const short8v*)(bb + nt * 1024);
                accg[0][nt] = __builtin_amdgcn_mfma_f32_16x16x32_bf16(af[0], bf_, accg[0][nt], 0, 0, 0);
                accg[1][nt] = __builtin_amdgcn_mfma_f32_16x16x32_bf16(af[1], bf_, accg[1][nt], 0, 0, 0);
            }
            __syncthreads();
        }

        // ---- + gb1, LN stat partials ----
        #pragma unroll
        for (int nt = 0; nt < 4; ++nt) {
            float bv = gb1[64 * w + 16 * nt + lc];
            #pragma unroll
            for (int rt = 0; rt < 2; ++rt)
                #pragma unroll
                for (int reg = 0; reg < 4; ++reg) accg[rt][nt][reg] += bv;
        }
        #pragma unroll
        for (int rt = 0; rt < 2; ++rt)
            #pragma unroll
            for (int reg = 0; reg < 4; ++reg) {
                float s1 = 0.f, s2 = 0.f;
                #pragma unroll
                for (int nt = 0; nt < 4; ++nt) { float v = accg[rt][nt][reg]; s1 += v; s2 += v * v; }
                #pragma unroll
                for (int off = 1; off < 16; off <<= 1) {
                    s1 += __shfl_xor(s1, off, 64);
                    s2 += __shfl_xor(s2, off, 64);
                }
                if (lc == 0) {
                    int r = 16 * rt + 4 * lg + reg;
                    sStat[w][r][0] = s1;
                    sStat[w][r][1] = s2;
                }
            }
        __syncthreads();

        float mug[2][4], rsg[2][4];
        #pragma unroll
        for (int rt = 0; rt < 2; ++rt)
            #pragma unroll
            for (int reg = 0; reg < 4; ++reg) {
                int r = 16 * rt + 4 * lg + reg;
                float s1 = 0.f, s2 = 0.f;
                #pragma unroll
                for (int ww = 0; ww < 8; ++ww) { s1 += sStat[ww][r][0]; s2 += sStat[ww][r][1]; }
                float m = s1 * (1.0f / 512.0f);
                float var = s2 * (1.0f / 512.0f) - m * m;
                mug[rt][reg] = m;
                rsg[rt][reg] = rsqrtf(var + 1e-5f);
            }

        // ---- LN + GELU + dot(gW2) ----
        float dp[2][4];
        #pragma unroll
        for (int rt = 0; rt < 2; ++rt)
            #pragma unroll
            for (int reg = 0; reg < 4; ++reg) dp[rt][reg] = 0.f;
        #pragma unroll
        for (int nt = 0; nt < 4; ++nt) {
            int col = 64 * w + 16 * nt + lc;
            float gv = glng[col], bv = glnb[col], wv = gW2[col];
            #pragma unroll
            for (int rt = 0; rt < 2; ++rt)
                #pragma unroll
                for (int reg = 0; reg < 4; ++reg) {
                    float v = (accg[rt][nt][reg] - mug[rt][reg]) * rsg[rt][reg] * gv + bv;
                    dp[rt][reg] += gelu_exact(v) * wv;
                }
        }
        #pragma unroll
        for (int rt = 0; rt < 2; ++rt)
            #pragma unroll
            for (int reg = 0; reg < 4; ++reg) {
                float d = dp[rt][reg];
                #pragma unroll
                for (int off = 1; off < 16; off <<= 1) d += __shfl_xor(d, off, 64);
                if (lc == 0) sDot[w][16 * rt + 4 * lg + reg] = d;
            }
        __syncthreads();
    }

    // ================= conflict epilogue =================
    if (tid < 32) {
        int r = tid;
        float z = gb2[0];
        #pragma unroll
        for (int ww = 0; ww < 8; ++ww) z += sDot[ww][r];
        float gs = 1.0f / (1.0f + expf(-z));
        float wv[8], mx = -1e30f;
        #pragma unroll
        for (int i = 0; i < 8; ++i) { wv[i] = aw[i]; mx = fmaxf(mx, wv[i]); }
        float sum = 0.f;
        #pragma unroll
        for (int i = 0; i < 8; ++i) { wv[i] = expf(wv[i] - mx); sum += wv[i]; }
        float inv = 1.0f / sum;
        float wsim = 0.f;
        #pragma unroll
        for (int i = 0; i < 8; ++i) wsim += sPa[r][i] * wv[i] * inv;
        float conf = 1.0f - (0.7f * wsim + 0.3f * gs);
        out_conflict[row0 + r] = fminf(fmaxf(conf, 0.0f), 1.0f);
    }
#undef STAGE
}

extern "C" void kernel_launch(void* const* d_in, const int* in_sizes, int n_in,
                              void* d_out, int out_size, void* d_ws, size_t ws_size,
                              hipStream_t stream) {
    const float* text  = (const float*)d_in[0];
    const float* image = (const float*)d_in[1];
    const float* W1    = (const float*)d_in[2];
    const float* b1    = (const float*)d_in[3];
    const float* ln1g  = (const float*)d_in[4];
    const float* ln1b  = (const float*)d_in[5];
    const float* W2    = (const float*)d_in[6];
    const float* b2    = (const float*)d_in[7];
    const float* aw    = (const float*)d_in[8];
    const float* gW1   = (const float*)d_in[9];
    const float* gb1   = (const float*)d_in[10];
    const float* glng  = (const float*)d_in[11];
    const float* glnb  = (const float*)d_in[12];
    const float* gW2   = (const float*)d_in[13];
    const float* gb2   = (const float*)d_in[14];

    unsigned short* W1c  = (unsigned short*)d_ws;                          // 1MB
    unsigned short* W2T  = (unsigned short*)((char*)d_ws + 1048576);       // 128KB
    unsigned short* gW1T = (unsigned short*)((char*)d_ws + 1179648);       // 1MB

    float* out = (float*)d_out;
    float* out_pa = out + B_TOTAL;

    convert_weights<<<544, 256, 0, stream>>>(W1, W2, gW1, W1c, W2T, gW1T);
    fused_all<<<2048, 512, 0, stream>>>(text, image, W1c, b1, ln1g, ln1b, W2T, b2,
                                        gW1T, gb1, glng, glnb, gW2, gb2, aw,
                                        out, out_pa);
}